// Round 6
// baseline (495.224 us; speedup 1.0000x reference)
//
#include <hip/hip_runtime.h>
#include <cmath>

// Problem constants (from reference)
#define NN  5      // N_NODES
#define BB  4      // batch
#define CCH 256    // channels
#define HWD 1024   // H*W
#define THRESH_V 0.3f
#define EPS_V 1e-12f

// R6: LDS-bandwidth fix. R5 counters showed ~88% LDS-pipe occupancy
// (15.7M ds_read_b128 @ ~12cyc ≈ 307us of the 368us). 4x4 frags read
// 2 B/FMA from LDS; 8x8 frags read 1 B/FMA. Each of 6 waves now owns a
// 64x64 tile of its stream (w<5: A[i]@x[w]; w5: W2[i]@x[i]).
// KC=16 keeps prefetch regs bounded (no launch-bounds min: R4 showed a
// VGPR clamp spills prefetch regs catastrophically).
#define CT 64      // channel rows per block
#define WT 64      // hw cols per block
#define KC 16      // k chunk
#define NCHUNK (CCH / KC)
#define APAD 68    // As/W2s row stride (floats)
#define ESP 68     // Es row stride (floats)

// smem (floats):
//  staging: Xs[5][16][64] @0 (5120) | As[16][68] @5120 (1088) | W2s @6208 (1088)
//  epilogue overlay: Es[6][32][68] = 13056 floats (52224 B), half-tile at a time
#define SMEM_FLOATS 13056

__global__ __launch_bounds__(384)
void fub_main(const float* __restrict__ x, const float* __restrict__ wmat,
              const float* __restrict__ conv_w, const float* __restrict__ conv_b,
              float* __restrict__ out)
{
    __shared__ __align__(16) float smem[SMEM_FLOATS];
    float* Xs  = smem;          // [5][KC][WT]
    float* As  = smem + 5120;   // [KC][APAD]
    float* W2s = smem + 6208;   // [KC][APAD]
    float* Es  = smem;          // [6][32][ESP] overlay (epilogue halves)

    const int tid  = threadIdx.x;
    const int wv   = tid >> 6;        // 0..5 : stream id
    const int lane = tid & 63;

    int bid = blockIdx.x;
    const int hwt = bid & 15; bid >>= 4;   // 16 hw tiles of 64
    const int b   = bid & 3;  bid >>= 2;   // 4 batches
    const int ct  = bid & 3;  bid >>= 2;   // 4 channel tiles of 64
    const int i   = bid;                   // 0..4

    const int c0  = ct * CT;
    const int hw0 = hwt * WT;

    const int lr = (lane >> 3) << 3;  // frag row base 0,8,...,56
    const int lc = (lane & 7)  << 3;  // frag col base 0,8,...,56

    // stream w<5 multiplies A by x[w]; stream 5 multiplies W2 by x[i]
    const int jx = (wv < 5) ? wv : i;
    const float* Mb = ((wv == 5) ? W2s : As) + lr;
    const float* Xb = Xs + jx * (KC * WT) + lc;

    float acc[8][8];
#pragma unroll
    for (int r = 0; r < 8; ++r)
#pragma unroll
        for (int c = 0; c < 8; ++c) acc[r][c] = 0.0f;

    // ---- prefetch state ----
    // x-loaders (tid<320): 4 float4.  weight-loaders (tid>=320): 8 float4.
    const bool xloader = (tid < 320);
    float4 pfa[4];
    float4 pfb[4];

    // ---- issue chunk 0 loads ----
    {
        if (xloader) {
#pragma unroll
            for (int it = 0; it < 4; ++it) {
                const int t   = tid + it * 320;       // 0..1279
                const int j   = t >> 8;               // 0..4
                const int rem = t & 255;
                const int kk  = rem >> 4;             // 0..15
                const int p4  = (rem & 15) << 2;      // 0..60
                pfa[it] = *(const float4*)(
                    x + (size_t)((j * BB + b) * CCH + kk) * HWD + hw0 + p4);
            }
        } else {
            const int u = tid - 320;                  // 0..63
#pragma unroll
            for (int it = 0; it < 4; ++it) {
                const int f  = u + (it << 6);         // 0..255
                const int r  = f >> 2;                // 0..63
                const int kq = (f & 3) << 2;          // 0,4,8,12
                const float* base =
                    conv_w + (size_t)(i * CCH + c0 + r) * (2 * CCH) + kq;
                pfa[it] = *(const float4*)(base);        // W1
                pfb[it] = *(const float4*)(base + CCH);  // W2
            }
        }
    }

    for (int ch = 0; ch < NCHUNK; ++ch) {
        if (ch) __syncthreads();   // prior compute done before LDS overwrite

        // ---- drain prefetch regs into LDS ----
        if (xloader) {
#pragma unroll
            for (int it = 0; it < 4; ++it) {
                const int t   = tid + it * 320;
                const int j   = t >> 8;
                const int rem = t & 255;
                const int kk  = rem >> 4;
                const int p4  = (rem & 15) << 2;
                *(float4*)(Xs + j * (KC * WT) + kk * WT + p4) = pfa[it];
            }
        } else {
            const int u = tid - 320;
#pragma unroll
            for (int it = 0; it < 4; ++it) {
                const int f  = u + (it << 6);
                const int r  = f >> 2;
                const int kq = (f & 3) << 2;
                const float4 w1 = pfa[it];
                const float4 w2 = pfb[it];
                As [(kq + 0) * APAD + r] = w1.x + w2.x;
                As [(kq + 1) * APAD + r] = w1.y + w2.y;
                As [(kq + 2) * APAD + r] = w1.z + w2.z;
                As [(kq + 3) * APAD + r] = w1.w + w2.w;
                W2s[(kq + 0) * APAD + r] = w2.x;
                W2s[(kq + 1) * APAD + r] = w2.y;
                W2s[(kq + 2) * APAD + r] = w2.z;
                W2s[(kq + 3) * APAD + r] = w2.w;
            }
        }
        __syncthreads();

        // ---- issue chunk ch+1's global loads (latency hidden by compute) ----
        if (ch + 1 < NCHUNK) {
            const int k0 = (ch + 1) * KC;
            if (xloader) {
#pragma unroll
                for (int it = 0; it < 4; ++it) {
                    const int t   = tid + it * 320;
                    const int j   = t >> 8;
                    const int rem = t & 255;
                    const int kk  = rem >> 4;
                    const int p4  = (rem & 15) << 2;
                    pfa[it] = *(const float4*)(
                        x + (size_t)((j * BB + b) * CCH + k0 + kk) * HWD + hw0 + p4);
                }
            } else {
                const int u = tid - 320;
#pragma unroll
                for (int it = 0; it < 4; ++it) {
                    const int f  = u + (it << 6);
                    const int r  = f >> 2;
                    const int kq = (f & 3) << 2;
                    const float* base =
                        conv_w + (size_t)(i * CCH + c0 + r) * (2 * CCH) + k0 + kq;
                    pfa[it] = *(const float4*)(base);
                    pfb[it] = *(const float4*)(base + CCH);
                }
            }
        }

        // ---- compute: 16 k-steps, 8x8 frag (64 FMAs per 64 B of LDS reads) ----
#pragma unroll
        for (int kk = 0; kk < KC; ++kk) {
            const float4 a0 = *(const float4*)(Mb + kk * APAD);
            const float4 a1 = *(const float4*)(Mb + kk * APAD + 4);
            const float4 x0 = *(const float4*)(Xb + kk * WT);
            const float4 x1 = *(const float4*)(Xb + kk * WT + 4);
            const float ar[8] = {a0.x, a0.y, a0.z, a0.w, a1.x, a1.y, a1.z, a1.w};
            const float xc[8] = {x0.x, x0.y, x0.z, x0.w, x1.x, x1.y, x1.z, x1.w};
#pragma unroll
            for (int r = 0; r < 8; ++r)
#pragma unroll
                for (int c = 0; c < 8; ++c)
                    acc[r][c] = fmaf(ar[r], xc[c], acc[r][c]);
        }
    }

    // ---- exchange + epilogue in two 32-row halves (Es overlays staging) ----
    float wrow[NN];
#pragma unroll
    for (int j = 0; j < NN; ++j) wrow[j] = wmat[i * NN + j];

#pragma unroll
    for (int h = 0; h < 2; ++h) {
        __syncthreads();   // LDS region free (main loop / prior half done)

        // waves write their acc rows belonging to this half: lanes with
        // lr in [32h, 32h+32) -> contiguous half-wave exec mask
        if ((lane >> 5) == h) {
            const int er0 = lr - (h << 5);           // 0,8,16,24
#pragma unroll
            for (int r = 0; r < 8; ++r) {
                float* p = Es + wv * (32 * ESP) + (er0 + r) * ESP + lc;
                *(float4*)(p)     = make_float4(acc[r][0], acc[r][1], acc[r][2], acc[r][3]);
                *(float4*)(p + 4) = make_float4(acc[r][4], acc[r][5], acc[r][6], acc[r][7]);
            }
        }
        __syncthreads();

        // epilogue: threads 0..255, 8 elements (2 float4) each
        if (tid < 256) {
            const int row  = tid >> 3;          // 0..31
            const int col8 = (tid & 7) << 3;    // 0,8,...,56
            const int c    = c0 + (h << 5) + row;
            const float bias = conv_b[i * CCH + c];

            const float* Tp = Es + 5 * (32 * ESP) + row * ESP + col8;
            const float4 T0 = *(const float4*)(Tp);
            const float4 T1 = *(const float4*)(Tp + 4);
            const float Tv[8] = {T0.x, T0.y, T0.z, T0.w, T1.x, T1.y, T1.z, T1.w};

            float num[8] = {0,0,0,0,0,0,0,0};
            float sq [8] = {0,0,0,0,0,0,0,0};
#pragma unroll
            for (int j = 0; j < NN; ++j) {
                const float* Sp = Es + j * (32 * ESP) + row * ESP + col8;
                const float4 s0 = *(const float4*)(Sp);
                const float4 s1 = *(const float4*)(Sp + 4);
                const float* xp = x + (size_t)((j * BB + b) * CCH + c) * HWD + hw0 + col8;
                const float4 xa = *(const float4*)(xp);
                const float4 xb = *(const float4*)(xp + 4);
                const float sv[8] = {s0.x, s0.y, s0.z, s0.w, s1.x, s1.y, s1.z, s1.w};
                const float xv[8] = {xa.x, xa.y, xa.z, xa.w, xb.x, xb.y, xb.z, xb.w};
                const float wj = wrow[j];
#pragma unroll
                for (int cc = 0; cc < 8; ++cc) {
                    const float dist = xv[cc] - (sv[cc] + Tv[cc] + bias);
                    const float z    = dist * wj;
                    float e = 1.0f / (1.0f + __expf(-z));
                    e = (e > THRESH_V) ? e : 0.0f;
                    sq[cc]  = fmaf(e, e, sq[cc]);
                    num[cc] = fmaf(e, xv[cc], num[cc]);
                }
            }
            float res[8];
#pragma unroll
            for (int cc = 0; cc < 8; ++cc)
                res[cc] = num[cc] / fmaxf(sqrtf(sq[cc]), EPS_V);

            float* op = out + (size_t)((i * BB + b) * CCH + c) * HWD + hw0 + col8;
            *(float4*)(op)     = make_float4(res[0], res[1], res[2], res[3]);
            *(float4*)(op + 4) = make_float4(res[4], res[5], res[6], res[7]);
        }
    }
}

extern "C" void kernel_launch(void* const* d_in, const int* in_sizes, int n_in,
                              void* d_out, int out_size, void* d_ws, size_t ws_size,
                              hipStream_t stream) {
    const float* x      = (const float*)d_in[0];
    const float* w      = (const float*)d_in[1];
    const float* conv_w = (const float*)d_in[2];
    const float* conv_b = (const float*)d_in[3];
    float* out = (float*)d_out;

    // grid: i(5) * ct(4) * b(4) * hwt(16) = 1280 blocks of 384 threads
    dim3 grid(1280);
    dim3 block(384);
    fub_main<<<grid, block, 0, stream>>>(x, w, conv_w, conv_b, out);
}

// Round 7
// 399.167 us; speedup vs baseline: 1.2406x; 1.2406x over previous
//
#include <hip/hip_runtime.h>
#include <cmath>

// Problem constants (from reference)
#define NN  5      // N_NODES
#define BB  4      // batch
#define CCH 256    // channels
#define HWD 1024   // H*W
#define THRESH_V 0.3f
#define EPS_V 1e-12f

// R7: 8x8 frag (1 B/FMA LDS traffic, half of R5's) under a strict VGPR
// budget. R6 proved the allocator caps at 128 VGPR and spills beyond it
// (FETCH 81MB/WRITE 121MB scratch). KC=8 shrinks prefetch state:
//   x-loaders (waves 0-4): 2 x float4 = 8 regs
//   weight-loader (wave 5): 4 x float4 = 16 regs (branch-disjoint with x path)
// Worst path ~= 64 acc + 16 pf + 16 frag + ~15 addr ~= 110 < 128 -> no spill.
#define CT 64      // channel rows per block
#define WT 64      // hw cols per block
#define KC 8       // k chunk
#define NCHUNK (CCH / KC)
#define APAD 68    // As/W2s row stride (floats)
#define ESP 68     // Es row stride (floats)

// smem (floats):
//  staging: Xs[5][8][64]=2560 @0 | As[8][68]=544 @2560 | W2s=544 @3104  (3648)
//  epilogue overlay: Es[6][32][68] = 13056 floats (52224 B), half-tile at a time
#define SMEM_FLOATS 13056

__global__ __launch_bounds__(384)
void fub_main(const float* __restrict__ x, const float* __restrict__ wmat,
              const float* __restrict__ conv_w, const float* __restrict__ conv_b,
              float* __restrict__ out)
{
    __shared__ __align__(16) float smem[SMEM_FLOATS];
    float* Xs  = smem;          // [5][KC][WT]
    float* As  = smem + 2560;   // [KC][APAD]
    float* W2s = smem + 3104;   // [KC][APAD]
    float* Es  = smem;          // [6][32][ESP] overlay (epilogue halves)

    const int tid  = threadIdx.x;
    const int wv   = tid >> 6;        // 0..5 : stream id
    const int lane = tid & 63;

    int bid = blockIdx.x;
    const int hwt = bid & 15; bid >>= 4;   // 16 hw tiles of 64
    const int b   = bid & 3;  bid >>= 2;   // 4 batches
    const int ct  = bid & 3;  bid >>= 2;   // 4 channel tiles of 64
    const int i   = bid;                   // 0..4

    const int c0  = ct * CT;
    const int hw0 = hwt * WT;

    const int lr = (lane >> 3) << 3;  // frag row base 0,8,...,56
    const int lc = (lane & 7)  << 3;  // frag col base 0,8,...,56

    // stream w<5 multiplies A by x[w]; stream 5 multiplies W2 by x[i]
    const int jx = (wv < 5) ? wv : i;
    const float* Mb = ((wv == 5) ? W2s : As) + lr;
    const float* Xb = Xs + jx * (KC * WT) + lc;

    float acc[8][8];
#pragma unroll
    for (int r = 0; r < 8; ++r)
#pragma unroll
        for (int c = 0; c < 8; ++c) acc[r][c] = 0.0f;

    // ---- prefetch state ----
    // x-loaders (tid<320): pfx[2].  weight-loader wave (tid>=320): pfw1[2]+pfw2[2].
    const bool xloader = (tid < 320);
    float4 pfx[2];
    float4 pfw1[2], pfw2[2];

    // chunk-invariant staging geometry
    // x: t = tid + it*320 (it<2), j=t>>7, rem=t&127, kk=rem>>4, p4=(rem&15)<<2
    // w: u = tid-320, row r=u, quads it*4
    const int u = tid - 320;
    const float* wgbase = conv_w + (size_t)(i * CCH + c0 + (u & 63)) * (2 * CCH);

    // ---- issue chunk 0 loads ----
    if (xloader) {
#pragma unroll
        for (int it = 0; it < 2; ++it) {
            const int t   = tid + it * 320;
            const int j   = t >> 7;
            const int rem = t & 127;
            const int kk  = rem >> 4;
            const int p4  = (rem & 15) << 2;
            pfx[it] = *(const float4*)(
                x + (size_t)((j * BB + b) * CCH + kk) * HWD + hw0 + p4);
        }
    } else {
#pragma unroll
        for (int it = 0; it < 2; ++it) {
            pfw1[it] = *(const float4*)(wgbase + (it << 2));
            pfw2[it] = *(const float4*)(wgbase + CCH + (it << 2));
        }
    }

    for (int ch = 0; ch < NCHUNK; ++ch) {
        if (ch) __syncthreads();   // prior compute done before LDS overwrite

        // ---- drain prefetch regs into LDS ----
        if (xloader) {
#pragma unroll
            for (int it = 0; it < 2; ++it) {
                const int t   = tid + it * 320;
                const int j   = t >> 7;
                const int rem = t & 127;
                const int kk  = rem >> 4;
                const int p4  = (rem & 15) << 2;
                *(float4*)(Xs + j * (KC * WT) + kk * WT + p4) = pfx[it];
            }
        } else {
#pragma unroll
            for (int it = 0; it < 2; ++it) {
                const float4 w1 = pfw1[it];
                const float4 w2 = pfw2[it];
                const int kb = it << 2;
                As [(kb + 0) * APAD + u] = w1.x + w2.x;
                As [(kb + 1) * APAD + u] = w1.y + w2.y;
                As [(kb + 2) * APAD + u] = w1.z + w2.z;
                As [(kb + 3) * APAD + u] = w1.w + w2.w;
                W2s[(kb + 0) * APAD + u] = w2.x;
                W2s[(kb + 1) * APAD + u] = w2.y;
                W2s[(kb + 2) * APAD + u] = w2.z;
                W2s[(kb + 3) * APAD + u] = w2.w;
            }
        }
        __syncthreads();

        // ---- issue chunk ch+1's global loads (latency hidden by compute) ----
        if (ch + 1 < NCHUNK) {
            const int k0 = (ch + 1) * KC;
            if (xloader) {
#pragma unroll
                for (int it = 0; it < 2; ++it) {
                    const int t   = tid + it * 320;
                    const int j   = t >> 7;
                    const int rem = t & 127;
                    const int kk  = rem >> 4;
                    const int p4  = (rem & 15) << 2;
                    pfx[it] = *(const float4*)(
                        x + (size_t)((j * BB + b) * CCH + k0 + kk) * HWD + hw0 + p4);
                }
            } else {
#pragma unroll
                for (int it = 0; it < 2; ++it) {
                    pfw1[it] = *(const float4*)(wgbase + k0 + (it << 2));
                    pfw2[it] = *(const float4*)(wgbase + CCH + k0 + (it << 2));
                }
            }
        }

        // ---- compute: 8 k-steps, 8x8 frag (64 FMAs per 64 B of LDS reads) ----
#pragma unroll
        for (int kk = 0; kk < KC; ++kk) {
            const float4 a0 = *(const float4*)(Mb + kk * APAD);
            const float4 a1 = *(const float4*)(Mb + kk * APAD + 4);
            const float4 x0 = *(const float4*)(Xb + kk * WT);
            const float4 x1 = *(const float4*)(Xb + kk * WT + 4);
            const float ar[8] = {a0.x, a0.y, a0.z, a0.w, a1.x, a1.y, a1.z, a1.w};
            const float xc[8] = {x0.x, x0.y, x0.z, x0.w, x1.x, x1.y, x1.z, x1.w};
#pragma unroll
            for (int r = 0; r < 8; ++r)
#pragma unroll
                for (int c = 0; c < 8; ++c)
                    acc[r][c] = fmaf(ar[r], xc[c], acc[r][c]);
        }
    }

    // ---- exchange + epilogue in two 32-row halves (Es overlays staging) ----
    float wrow[NN];
#pragma unroll
    for (int j = 0; j < NN; ++j) wrow[j] = wmat[i * NN + j];

#pragma unroll
    for (int h = 0; h < 2; ++h) {
        __syncthreads();   // LDS region free (main loop / prior half done)

        // waves write their acc rows belonging to this half
        if ((lane >> 5) == h) {
            const int er0 = lr - (h << 5);           // 0,8,16,24
#pragma unroll
            for (int r = 0; r < 8; ++r) {
                float* p = Es + wv * (32 * ESP) + (er0 + r) * ESP + lc;
                *(float4*)(p)     = make_float4(acc[r][0], acc[r][1], acc[r][2], acc[r][3]);
                *(float4*)(p + 4) = make_float4(acc[r][4], acc[r][5], acc[r][6], acc[r][7]);
            }
        }
        __syncthreads();

        // epilogue: threads 0..255, 8 elements (2 float4) each
        if (tid < 256) {
            const int row  = tid >> 3;          // 0..31
            const int col8 = (tid & 7) << 3;    // 0,8,...,56
            const int c    = c0 + (h << 5) + row;
            const float bias = conv_b[i * CCH + c];

            const float* Tp = Es + 5 * (32 * ESP) + row * ESP + col8;
            const float4 T0 = *(const float4*)(Tp);
            const float4 T1 = *(const float4*)(Tp + 4);
            const float Tv[8] = {T0.x, T0.y, T0.z, T0.w, T1.x, T1.y, T1.z, T1.w};

            float num[8] = {0,0,0,0,0,0,0,0};
            float sq [8] = {0,0,0,0,0,0,0,0};
#pragma unroll
            for (int j = 0; j < NN; ++j) {
                const float* Sp = Es + j * (32 * ESP) + row * ESP + col8;
                const float4 s0 = *(const float4*)(Sp);
                const float4 s1 = *(const float4*)(Sp + 4);
                const float* xp = x + (size_t)((j * BB + b) * CCH + c) * HWD + hw0 + col8;
                const float4 xa = *(const float4*)(xp);
                const float4 xb = *(const float4*)(xp + 4);
                const float sv[8] = {s0.x, s0.y, s0.z, s0.w, s1.x, s1.y, s1.z, s1.w};
                const float xv[8] = {xa.x, xa.y, xa.z, xa.w, xb.x, xb.y, xb.z, xb.w};
                const float wj = wrow[j];
#pragma unroll
                for (int cc = 0; cc < 8; ++cc) {
                    const float dist = xv[cc] - (sv[cc] + Tv[cc] + bias);
                    const float z    = dist * wj;
                    float e = 1.0f / (1.0f + __expf(-z));
                    e = (e > THRESH_V) ? e : 0.0f;
                    sq[cc]  = fmaf(e, e, sq[cc]);
                    num[cc] = fmaf(e, xv[cc], num[cc]);
                }
            }
            float res[8];
#pragma unroll
            for (int cc = 0; cc < 8; ++cc)
                res[cc] = num[cc] / fmaxf(sqrtf(sq[cc]), EPS_V);

            float* op = out + (size_t)((i * BB + b) * CCH + c) * HWD + hw0 + col8;
            *(float4*)(op)     = make_float4(res[0], res[1], res[2], res[3]);
            *(float4*)(op + 4) = make_float4(res[4], res[5], res[6], res[7]);
        }
    }
}

extern "C" void kernel_launch(void* const* d_in, const int* in_sizes, int n_in,
                              void* d_out, int out_size, void* d_ws, size_t ws_size,
                              hipStream_t stream) {
    const float* x      = (const float*)d_in[0];
    const float* w      = (const float*)d_in[1];
    const float* conv_w = (const float*)d_in[2];
    const float* conv_b = (const float*)d_in[3];
    float* out = (float*)d_out;

    // grid: i(5) * ct(4) * b(4) * hwt(16) = 1280 blocks of 384 threads
    dim3 grid(1280);
    dim3 block(384);
    fub_main<<<grid, block, 0, stream>>>(x, w, conv_w, conv_b, out);
}